// Round 15
// baseline (247.236 us; speedup 1.0000x reference)
//
#include <hip/hip_runtime.h>
#include <math.h>

// Problem constants
#define BN 256
#define TN 64
#define LN 32
#define DN 128
#define SN 4
#define HN 32   // column-panel width for the blocked elimination

#define LOG2PI 1.8378770664093453f

__device__ __forceinline__ float bcastf(float v, int lane) {
    return __builtin_bit_cast(float, __builtin_amdgcn_readlane(__builtin_bit_cast(int, v), lane));
}

// Intra-wave LDS ordering fence (R13-proven correct): DS pipe is in-order per
// wave; this stops the COMPILER from moving LDS reads across the masked
// publish. Zero runtime cost.
__device__ __forceinline__ void wavefence() {
    __builtin_amdgcn_wave_barrier();
    asm volatile("" ::: "memory");
}

// ===========================================================================
// Lessons R1-R14:
//  * v_readlane issues at ~8 cyc (trans-rate) -> the ~2.1k sweep readlanes
//    are 80% of k_chol's issue cycles (R8/R11/R14 busy-cycle arithmetic).
//  * Fix: pivot-row broadcast via LDS publish (masked ds_write_b128) +
//    same-address ds_read_b128 (DS pipe, 4 values/instr). Publish+fence
//    correctness proven R13; runtime loops proven R14 (keeps code I$-small,
//    VGPR low); fused-shift (pivot col at r[0]) avoids runtime register
//    indices and auto-aligns the published row to the shifted window.
//  * Triangularity via 4 sub-blocks with static chunk counts NC = 8-2P.
// ===========================================================================

// LDS plane layout for staging: [32 rows][8 chunks][4 dwords]; chunk q of
// row i at position (q + i + (i>>3)) & 7 -> conflict-free fills & stores.
__device__ __forceinline__ int chunk_pos(int q, int i) { return (q + i + (i >> 3)) & 7; }

template<int Q>
__device__ __forceinline__ void fillp(float (&r)[HN], const float* plane, int slot) {
    if constexpr (Q < 8) {
        const float4 v = *(const float4*)(plane + slot * 32 + chunk_pos(Q, slot) * 4);
        r[4 * Q + 0] = v.x; r[4 * Q + 1] = v.y;
        r[4 * Q + 2] = v.z; r[4 * Q + 3] = v.w;
        fillp<Q + 1>(r, plane, slot);
    }
}
// trace: tr += <kinv_row, r>; sm += <kinv_row, mu_vec> (mu from per-wave LDS)
template<int JB, int J4>
__device__ __forceinline__ void trace_lds(const float (&r)[HN], const float* __restrict__ kp,
                                          const float* mudp, float& tr, float& sm) {
    if constexpr (J4 < 8) {
        float4 kv = *(const float4*)(kp + 4 * J4);
        float4 mv = *(const float4*)(mudp + JB + 4 * J4);
        tr = fmaf(kv.x, r[4 * J4 + 0], tr); sm = fmaf(kv.x, mv.x, sm);
        tr = fmaf(kv.y, r[4 * J4 + 1], tr); sm = fmaf(kv.y, mv.y, sm);
        tr = fmaf(kv.z, r[4 * J4 + 2], tr); sm = fmaf(kv.z, mv.z, sm);
        tr = fmaf(kv.w, r[4 * J4 + 3], tr); sm = fmaf(kv.w, mv.w, sm);
        trace_lds<JB, J4 + 1>(r, kp, mudp, tr, sm);
    }
}

// ---------------------------------------------------------------------------
// Pivot sub-block: 8 steps, publisher lane = LOFF+K, live chunks NC = 8-2P.
// Fused shift: r[s-1] = r[s] - c*P[s]; col K always at r[0]; published row
// (same shifts applied by the publisher) is index-aligned with consumers.
// Publisher's own update (c = d/d = 1) self-zeroes its row -> dead, correct.
// ---------------------------------------------------------------------------
template<int P, bool STOREC, int LOFF>
__device__ __forceinline__ void sweep8(float (&r)[HN], float& logdet,
                                       float* pubp, unsigned short* cpw,
                                       int lane, int tid) {
    constexpr int NC = 8 - 2 * P;        // chunks live in this sub-block
#pragma unroll 1
    for (int k8 = 0; k8 < 8; ++k8) {
        int K = 8 * P + k8;
        if (lane == LOFF + K) {
#pragma unroll
            for (int cq = 0; cq < NC; ++cq)
                *(float4*)(pubp + 4 * cq) =
                    make_float4(r[4 * cq + 0], r[4 * cq + 1], r[4 * cq + 2], r[4 * cq + 3]);
        }
        wavefence();                     // publish visible before reads
        float4 p0 = *(const float4*)pubp;
        float d = p0.x;
        logdet += __logf(d);
        float c = r[0] * __builtin_amdgcn_rcpf(d);
        if constexpr (STOREC)            // bf16 multiplier -> c-panel [K][tid]
            cpw[K * 256 + tid] = (unsigned short)(__builtin_bit_cast(unsigned, c) >> 16);
        // shift update, chunk 0 (skip s=0: col K retires)
        r[0] = fmaf(-c, p0.y, r[1]);
        r[1] = fmaf(-c, p0.z, r[2]);
        r[2] = fmaf(-c, p0.w, r[3]);
#pragma unroll
        for (int cq = 1; cq < NC; ++cq) {
            float4 pp = *(const float4*)(pubp + 4 * cq);
            r[4 * cq - 1] = fmaf(-c, pp.x, r[4 * cq + 0]);
            r[4 * cq + 0] = fmaf(-c, pp.y, r[4 * cq + 1]);
            r[4 * cq + 1] = fmaf(-c, pp.z, r[4 * cq + 2]);
            r[4 * cq + 2] = fmaf(-c, pp.w, r[4 * cq + 3]);
        }
        wavefence();                     // reads done before next publish
    }
}

// ---------------------------------------------------------------------------
// k_chol: block = 256 threads = 4 waves = one (b, l-quad).
// LDS: 16KB staging + 16KB bf16 c-panel + pub/mu ~1.7KB = ~33.7KB -> 4/CU.
// ---------------------------------------------------------------------------
__global__ __launch_bounds__(256)
void k_chol(const float* __restrict__ Sg,
            const float* __restrict__ mus,
            const float* __restrict__ kinv,
            const float* __restrict__ logdetK,
            float* __restrict__ out) {
    __shared__ float st[4 * 1024];            // 16 KB staging
    __shared__ unsigned short cp16[32 * 256]; // 16 KB bf16 c-panel [K][tid]
    __shared__ float pubs[4][36];             // per-wave pivot-row buffer
    __shared__ float muds[4][64];             // per-wave mu vector

    int hw = blockIdx.x;                 // 2048 blocks
    int g = (hw & 7) * 256 + (hw >> 3);  // XCD x owns b in [x*32, x*32+32)
    int b = g >> 3, lg = g & 7;          // lg = l-quad 0..7

    int tid = threadIdx.x;
    int w = tid >> 6, lane = tid & 63;   // wave w <-> l = lg*4 + w; lane = row
    int l = lg * 4 + w;
    int slot = lane & 31;                // row within the staged half

    float mu = mus[((size_t)b * TN + lane) * LN + l];
    muds[w][lane] = mu;                  // read after staging barriers
    const float* kp = kinv + l * (TN * TN) + lane * TN;
    const float* plane = &st[w * 1024];
    float* pubp = &pubs[w][0];
    const float* mudp = &muds[w][0];

    // stage a 32-row x 32-col half-panel (rows r0..r0+31, cols c0..c0+31)
    auto stage = [&](int r0, int c0) {
#pragma unroll
        for (int it = 0; it < 4; ++it) {
            int m_ = tid + it * 256;     // 0..1023
            int j = m_ & 31, i = m_ >> 5;
            const float* gp = Sg + ((((size_t)b * TN + r0 + i) * TN + c0 + j) * LN + lg * 4);
            float4 v = *(const float4*)gp;
            int off = i * 32 + chunk_pos(j >> 2, i) * 4 + (j & 3);
            st[0 * 1024 + off] = v.x;
            st[1 * 1024 + off] = v.y;
            st[2 * 1024 + off] = v.z;
            st[3 * 1024 + off] = v.w;
        }
    };

    float tr = 0.0f, sm = 0.0f, logdet = 0.0f;
    float r1[HN];

    // ---- panel 1 (cols 0..31) ----
    stage(0, 0);
    __syncthreads();
    if (lane < 32) fillp<0>(r1, plane, slot);
    __syncthreads();
    stage(32, 0);
    __syncthreads();
    if (lane >= 32) fillp<0>(r1, plane, slot);

    trace_lds<0, 0>(r1, kp, mudp, tr, sm);

    // c1 sweep: pivots 0..31 (publisher lane K), mults -> c-panel
    sweep8<0, true, 0>(r1, logdet, pubp, cp16, lane, tid);
    sweep8<1, true, 0>(r1, logdet, pubp, cp16, lane, tid);
    sweep8<2, true, 0>(r1, logdet, pubp, cp16, lane, tid);
    sweep8<3, true, 0>(r1, logdet, pubp, cp16, lane, tid);

    // ---- panel 2 (cols 32..63) ----
    __syncthreads();                     // all waves done with panel-1 LDS
    float r2[HN];
    stage(0, 32);
    __syncthreads();
    if (lane < 32) fillp<0>(r2, plane, slot);
    __syncthreads();
    stage(32, 32);
    __syncthreads();
    if (lane >= 32) fillp<0>(r2, plane, slot);

    trace_lds<32, 0>(r2, kp + 32, mudp, tr, sm);

    // replay pivots 0..31 onto cols 32..63: publisher lane K publishes its
    // r2 (exact through step K-1 = the pivot row); c = own bf16 multiplier.
#pragma unroll 1
    for (int K = 0; K < HN; ++K) {
        if (lane == K) {
#pragma unroll
            for (int cq = 0; cq < 8; ++cq)
                *(float4*)(pubp + 4 * cq) =
                    make_float4(r2[4 * cq + 0], r2[4 * cq + 1], r2[4 * cq + 2], r2[4 * cq + 3]);
        }
        wavefence();
        float c = __builtin_bit_cast(float, (unsigned)cp16[K * 256 + tid] << 16);
#pragma unroll
        for (int cq = 0; cq < 8; ++cq) {
            float4 pp = *(const float4*)(pubp + 4 * cq);
            r2[4 * cq + 0] = fmaf(-c, pp.x, r2[4 * cq + 0]);
            r2[4 * cq + 1] = fmaf(-c, pp.y, r2[4 * cq + 1]);
            r2[4 * cq + 2] = fmaf(-c, pp.z, r2[4 * cq + 2]);
            r2[4 * cq + 3] = fmaf(-c, pp.w, r2[4 * cq + 3]);
        }
        wavefence();
    }

    // solo pivots 32..63 on trailing 32x32 (publisher lane 32+K)
    sweep8<0, false, 32>(r2, logdet, pubp, cp16, lane, tid);
    sweep8<1, false, 32>(r2, logdet, pubp, cp16, lane, tid);
    sweep8<2, false, 32>(r2, logdet, pubp, cp16, lane, tid);
    sweep8<3, false, 32>(r2, logdet, pubp, cp16, lane, tid);

    float contrib = tr + mu * sm;
#pragma unroll
    for (int off = 32; off >= 1; off >>= 1) contrib += __shfl_xor(contrib, off, 64);

    if (lane == 0) {
        float klp = 0.5f * (logdetK[l] - logdet - (float)TN + contrib);
        atomicAdd(&out[b], klp);
    }
}

// ======================== fused k_ll + k_kinv (R11, unchanged) =============
template<int J>
__device__ __forceinline__ void pan_load(float (&p)[HN], const float* __restrict__ Kmat,
                                         int i, int l, int jbase) {
    if constexpr (J < HN) {
        p[J] = Kmat[(i * TN + jbase + J) * LN + l];
        pan_load<J + 1>(p, Kmat, i, l, jbase);
    }
}
template<int K, int J>
__device__ __forceinline__ void ki_upd(float (&a)[HN], float c) {
    if constexpr (J < HN) {
        a[J] = fmaf(-c, bcastf(a[J], K), a[J]);
        ki_upd<K, J + 1>(a, c);
    }
}
template<int K>
__device__ __forceinline__ void ki_a1sweep(float (&a1)[HN], float& ld, float& piv, int i) {
    if constexpr (K < HN) {
        float dkk = bcastf(a1[K], K);
        ld += __logf(dkk);
        if (i == K) piv = dkk;
        float c = (i == K) ? 0.0f : a1[K] * __builtin_amdgcn_rcpf(dkk);
        ki_upd<K, K + 1>(a1, c);
        a1[K] = c;
        ki_a1sweep<K + 1>(a1, ld, piv, i);
    }
}
template<int K>
__device__ __forceinline__ void ki_replay(float (&a2)[HN], const float (&a1)[HN]) {
    if constexpr (K < HN) {
        ki_upd<K, 0>(a2, a1[K]);
        ki_replay<K + 1>(a2, a1);
    }
}
template<int Q, int J>
__device__ __forceinline__ void ki_upd2(float (&a2)[HN], float c) {
    if constexpr (J < HN) {
        a2[J] = fmaf(-c, bcastf(a2[J], 32 + Q), a2[J]);
        ki_upd2<Q, J + 1>(a2, c);
    }
}
template<int Q>
__device__ __forceinline__ void ki_a2sweep(float (&a2)[HN], float& ld, float& piv, int i) {
    if constexpr (Q < HN) {
        float dkk = bcastf(a2[Q], 32 + Q);
        ld += __logf(dkk);
        if (i == 32 + Q) piv = dkk;
        float c = (i == 32 + Q) ? 0.0f : a2[Q] * __builtin_amdgcn_rcpf(dkk);
        ki_upd2<Q, Q + 1>(a2, c);
        a2[Q] = c;
        ki_a2sweep<Q + 1>(a2, ld, piv, i);
    }
}
template<int J>
__device__ __forceinline__ void g1_init(float (&g)[HN], int i) {
    if constexpr (J < HN) { g[J] = (J == i) ? 1.0f : 0.0f; g1_init<J + 1>(g, i); }
}
template<int K, int J>
__device__ __forceinline__ void g1_updA(float (&g)[HN], float c) {
    if constexpr (J <= K) {
        g[J] = fmaf(-c, bcastf(g[J], K), g[J]);
        g1_updA<K, J + 1>(g, c);
    }
}
template<int K>
__device__ __forceinline__ void g1_phase1(float (&g)[HN], const float (&a1)[HN]) {
    if constexpr (K < HN) {
        g1_updA<K, 0>(g, a1[K]);
        g1_phase1<K + 1>(g, a1);
    }
}
template<int Q, int J>
__device__ __forceinline__ void g1_updB(float (&g)[HN], float c) {
    if constexpr (J < HN) {
        g[J] = fmaf(-c, bcastf(g[J], 32 + Q), g[J]);
        g1_updB<Q, J + 1>(g, c);
    }
}
template<int Q>
__device__ __forceinline__ void g1_phase2(float (&g)[HN], const float (&a2)[HN]) {
    if constexpr (Q < HN) {
        g1_updB<Q, 0>(g, a2[Q]);
        g1_phase2<Q + 1>(g, a2);
    }
}
template<int J>
__device__ __forceinline__ void g2_init(float (&g)[HN], int i) {
    if constexpr (J < HN) { g[J] = (32 + J == i) ? 1.0f : 0.0f; g2_init<J + 1>(g, i); }
}
template<int Q, int J>
__device__ __forceinline__ void g2_upd(float (&g)[HN], float c) {
    if constexpr (J <= Q) {
        g[J] = fmaf(-c, bcastf(g[J], 32 + Q), g[J]);
        g2_upd<Q, J + 1>(g, c);
    }
}
template<int Q>
__device__ __forceinline__ void g2_phase(float (&g)[HN], const float (&a2)[HN]) {
    if constexpr (Q < HN) {
        g2_upd<Q, 0>(g, a2[Q]);
        g2_phase<Q + 1>(g, a2);
    }
}
template<int J>
__device__ __forceinline__ void pan_out(const float (&g)[HN], float rdi,
                                        float* __restrict__ dst) {
    if constexpr (J < HN) {
        dst[J] = g[J] * rdi;
        pan_out<J + 1>(g, rdi, dst);
    }
}

__global__ __launch_bounds__(256)
void k_ll_kinv(const float* __restrict__ X,
               const float* __restrict__ Mn,
               const float* __restrict__ R,
               const float* __restrict__ Kmat,
               float* __restrict__ kinv,
               float* __restrict__ logdetK,
               float* __restrict__ out) {
    if (blockIdx.x < 64) {
        // 2 blocks per latent: both redo the sweeps, split the reconstruction
        if (threadIdx.x >= 64) return;
        const int l = blockIdx.x >> 1;
        const int half = blockIdx.x & 1;
        const int i = threadIdx.x;       // row

        float ld = 0.0f, piv = 1.0f;
        float a1[HN], a2[HN];
        pan_load<0>(a1, Kmat, i, l, 0);
        ki_a1sweep<0>(a1, ld, piv, i);
        pan_load<0>(a2, Kmat, i, l, 32);
        ki_replay<0>(a2, a1);
        ki_a2sweep<0>(a2, ld, piv, i);
        float rdi = __builtin_amdgcn_rcpf(piv);
        if (half == 0) {
            float g1[HN];
            g1_init<0>(g1, i);
            g1_phase1<0>(g1, a1);
            g1_phase2<0>(g1, a2);
            pan_out<0>(g1, rdi, kinv + l * (TN * TN) + i * TN);
        } else {
            float g2[HN];
            g2_init<0>(g2, i);
            g2_phase<0>(g2, a2);
            pan_out<0>(g2, rdi, kinv + l * (TN * TN) + i * TN + 32);
            if (i == 0) logdetK[l] = ld;
        }
        return;
    }

    // ---- log-likelihood block (b,s) ----
    int hw = blockIdx.x - 64;            // 1024 blocks
    int g = (hw & 7) * 128 + (hw >> 3);
    int b = g >> 2, s = g & 3;
    int tid = threadIdx.x;

    const float4* xp = (const float4*)(X + (size_t)b * TN * DN);
    const float4* mp = (const float4*)(Mn + ((size_t)(b * SN + s) * TN) * DN);

    int c = tid & 31;
    float4 rv = ((const float4*)R)[c];
    float4 ri = make_float4(1.0f / rv.x, 1.0f / rv.y, 1.0f / rv.z, 1.0f / rv.w);

    float acc = 0.0f;
#pragma unroll
    for (int it = 0; it < (TN * DN / 4) / 256; ++it) {
        int f = tid + it * 256;
        float4 xv = xp[f];
        float4 mv = mp[f];
        float dx = xv.x - mv.x; acc = fmaf(dx * dx, ri.x, acc);
        float dy = xv.y - mv.y; acc = fmaf(dy * dy, ri.y, acc);
        float dz = xv.z - mv.z; acc = fmaf(dz * dz, ri.z, acc);
        float dw = xv.w - mv.w; acc = fmaf(dw * dw, ri.w, acc);
    }
#pragma unroll
    for (int off = 32; off >= 1; off >>= 1) acc += __shfl_xor(acc, off, 64);

    __shared__ float wsum[4];
    if ((tid & 63) == 0) wsum[tid >> 6] = acc;
    __syncthreads();
    if (tid == 0) {
        float q = wsum[0] + wsum[1] + wsum[2] + wsum[3];
        float val = q * (0.5f / SN);
        if (s == 0) {
            float slr = 0.0f;
#pragma unroll
            for (int d = 0; d < DN; ++d) slr += __logf(R[d]);
            val += 0.5f * (float)TN * (slr + (float)DN * LOG2PI);
        }
        atomicAdd(&out[b], val);
    }
}

// ---------------------------------------------------------------------------
extern "C" void kernel_launch(void* const* d_in, const int* in_sizes, int n_in,
                              void* d_out, int out_size, void* d_ws, size_t ws_size,
                              hipStream_t stream) {
    const float* X   = (const float*)d_in[0];  // [B,T,D]
    const float* Mn  = (const float*)d_in[1];  // [B,S,T,D]
    const float* R   = (const float*)d_in[2];  // [D]
    const float* mus = (const float*)d_in[3];  // [B,T,L]
    const float* Sg  = (const float*)d_in[4];  // [B,T,T,L]
    const float* Km  = (const float*)d_in[5];  // [T,T,L]
    float* out = (float*)d_out;                // [B] fp32

    float* kinv = (float*)d_ws;                // 32*4096 floats = 512 KB
    float* ldK  = kinv + LN * TN * TN;         // 32 floats

    hipMemsetAsync(d_out, 0, BN * sizeof(float), stream);
    k_ll_kinv<<<64 + BN * SN, 256, 0, stream>>>(X, Mn, R, Km, kinv, ldK, out);
    k_chol<<<BN * 8, 256, 0, stream>>>(Sg, mus, kinv, ldK, out);
}

// Round 16
// 139.634 us; speedup vs baseline: 1.7706x; 1.7706x over previous
//
#include <hip/hip_runtime.h>
#include <math.h>

// Problem constants
#define BN 256
#define TN 64
#define LN 32
#define DN 128
#define SN 4
#define HN 32   // column-panel width for the blocked elimination

#define LOG2PI 1.8378770664093453f

__device__ __forceinline__ float bcastf(float v, int lane) {
    return __builtin_bit_cast(float, __builtin_amdgcn_readlane(__builtin_bit_cast(int, v), lane));
}
// Broadcast lane `K`'s value of v to all lanes via the LDS crossbar
// (ds_bpermute: VGPR->VGPR, no SGPR hazard, no LDS storage, no fences —
// ordering is plain register SSA). addr is uniform K*4.
__device__ __forceinline__ float bperm(int addr, float v) {
    return __builtin_bit_cast(float, __builtin_amdgcn_ds_bpermute(addr, __builtin_bit_cast(int, v)));
}

// ===========================================================================
// Lessons R1-R15:
//  * Register-array subscripts must be compile-time constants (templates);
//    min-occupancy attrs -> scratch storm (R9); f32x2/asm -> VGPR bloat
//    (R10); per-step LDS publish -> round-trip latency serializes the
//    96-step chain (R13 unrolled, R15 looped — both lost).
//  * v_readlane costs ~8 issue cycles (R8/R11/R14 busy-cycle fits) -> the
//    ~2.1k sweep readlanes are 80% of k_chol. THIS round: replace them with
//    ds_bpermute broadcasts in the TEXTBOOK formulation (pull pivot row
//    from lane K -> uniform addr per step). Pure register dataflow: the
//    bpermute source reads pre-update SSA values; pivot rows self-zero
//    (c=1) and later multipliers are exactly 0. Base structure = R8's
//    proven 117us kernel verbatim.
// ===========================================================================

// LDS plane layout: [64 rows][8 chunks][4 dwords]; chunk q of row i at
// position (q + i + (i>>3)) & 7 -> conflict-free b128 fills & staging stores.
__device__ __forceinline__ int chunk_pos(int q, int i) { return (q + i + (i >> 3)) & 7; }

// ---- shared template helpers (R8-proven) ---------------------------------
template<int Q>
__device__ __forceinline__ void fillp(float (&r)[HN], const float* plane, int l) {
    if constexpr (Q < 8) {
        const float4 v = *(const float4*)(plane + l * 32 + chunk_pos(Q, l) * 4);
        r[4 * Q + 0] = v.x; r[4 * Q + 1] = v.y;
        r[4 * Q + 2] = v.z; r[4 * Q + 3] = v.w;
        fillp<Q + 1>(r, plane, l);
    }
}
template<int JBASE, int J4>
__device__ __forceinline__ void trace_half(const float (&r)[HN], const float* __restrict__ kp,
                                           float mu, float& tr, float& sm) {
    if constexpr (J4 < 8) {
        float4 kv = *(const float4*)(kp + 4 * J4);
        tr = fmaf(kv.x, r[4 * J4 + 0], tr); sm = fmaf(kv.x, bcastf(mu, JBASE + 4 * J4 + 0), sm);
        tr = fmaf(kv.y, r[4 * J4 + 1], tr); sm = fmaf(kv.y, bcastf(mu, JBASE + 4 * J4 + 1), sm);
        tr = fmaf(kv.z, r[4 * J4 + 2], tr); sm = fmaf(kv.z, bcastf(mu, JBASE + 4 * J4 + 2), sm);
        tr = fmaf(kv.w, r[4 * J4 + 3], tr); sm = fmaf(kv.w, bcastf(mu, JBASE + 4 * J4 + 3), sm);
        trace_half<JBASE, J4 + 1>(r, kp, mu, tr, sm);
    }
}

// ---- k_chol sweeps: textbook elimination, bpermute pivot-row pulls -------
// Step K: every lane pulls pivot-row elements from lane K (uniform addr K*4).
// Lane K's row is exact through step K-1; its own update (c = d/d = 1)
// self-zeroes the row, and its later multipliers are exactly 0.
template<int K, int J>
__device__ __forceinline__ void c1_upd(float (&r1)[HN], float c) {
    if constexpr (J < HN) {
        r1[J] = fmaf(-c, bperm(K << 2, r1[J]), r1[J]);
        c1_upd<K, J + 1>(r1, c);
    }
}
template<int K>
__device__ __forceinline__ void c1_sweep(float (&r1)[HN], float& logdet) {
    if constexpr (K < HN) {
        float d = bperm(K << 2, r1[K]);      // pivot (lane K's diagonal)
        logdet += __logf(d);
        float c = r1[K] * __builtin_amdgcn_rcpf(d);
        c1_upd<K, K + 1>(r1, c);             // triangular: cols > K only
        r1[K] = c;                           // multiplier -> dead slot
        c1_sweep<K + 1>(r1, logdet);
    }
}
// replay pivots 0..31 onto cols 32..63; pivot row K's right half = lane K's
// r2 (exact through step K-1); c = own stored multiplier (lane K's is 1 ->
// self-zero; zero rows have multiplier 0 -> stay zero).
template<int K, int J>
__device__ __forceinline__ void rep_upd(float (&r2)[HN], float c) {
    if constexpr (J < HN) {
        r2[J] = fmaf(-c, bperm(K << 2, r2[J]), r2[J]);
        rep_upd<K, J + 1>(r2, c);
    }
}
template<int K>
__device__ __forceinline__ void rep_sweep(float (&r2)[HN], const float (&r1)[HN]) {
    if constexpr (K < HN) {
        rep_upd<K, 0>(r2, r1[K]);
        rep_sweep<K + 1>(r2, r1);
    }
}
// pivots 32..63 on trailing 32x32: pivot row = lane 32+Q
template<int Q, int J>
__device__ __forceinline__ void solo_upd(float (&r2)[HN], float c) {
    if constexpr (J < HN) {
        r2[J] = fmaf(-c, bperm((32 + Q) << 2, r2[J]), r2[J]);
        solo_upd<Q, J + 1>(r2, c);
    }
}
template<int Q>
__device__ __forceinline__ void solo_sweep(float (&r2)[HN], float& logdet) {
    if constexpr (Q < HN) {
        float d = bperm((32 + Q) << 2, r2[Q]);
        logdet += __logf(d);
        float c = r2[Q] * __builtin_amdgcn_rcpf(d);
        solo_upd<Q, Q + 1>(r2, c);           // triangular
        solo_sweep<Q + 1>(r2, logdet);
    }
}

// ---------------------------------------------------------------------------
// k_chol: block = 256 threads = 4 waves = one (b, l-quad). R8's proven
// staging: 4 planes x 64x32 panel = 32 KB, reused panel1 -> panel2.
// ---------------------------------------------------------------------------
__global__ __launch_bounds__(256)
void k_chol(const float* __restrict__ Sg,
            const float* __restrict__ mus,
            const float* __restrict__ kinv,
            const float* __restrict__ logdetK,
            float* __restrict__ out) {
    __shared__ float st[4 * 2048];       // 32 KB

    int hw = blockIdx.x;                 // 2048 blocks
    int g = (hw & 7) * 256 + (hw >> 3);  // XCD x owns b in [x*32, x*32+32)
    int b = g >> 3, lg = g & 7;          // lg = l-quad 0..7

    int tid = threadIdx.x;
    int w = tid >> 6, lane = tid & 63;   // wave w <-> l = lg*4 + w; lane = row
    int l = lg * 4 + w;

    float mu = mus[((size_t)b * TN + lane) * LN + l];
    const float* kp = kinv + l * (TN * TN) + lane * TN;
    const float* plane = &st[w * 2048];

    // stage a 64-row x 32-col panel (cols c0..c0+31)
    auto stage = [&](int c0) {
#pragma unroll
        for (int it = 0; it < 8; ++it) {
            int m_ = tid + it * 256;     // 0..2047
            int j = m_ & 31, i = m_ >> 5;
            const float* gp = Sg + ((((size_t)b * TN + i) * TN + c0 + j) * LN + lg * 4);
            float4 v = *(const float4*)gp;
            int off = i * 32 + chunk_pos(j >> 2, i) * 4 + (j & 3);
            st[0 * 2048 + off] = v.x;
            st[1 * 2048 + off] = v.y;
            st[2 * 2048 + off] = v.z;
            st[3 * 2048 + off] = v.w;
        }
    };

    float tr = 0.0f, sm = 0.0f, logdet = 0.0f;
    float r1[HN];

    // ---- panel 1 (cols 0..31) ----
    stage(0);
    __syncthreads();
    fillp<0>(r1, plane, lane);

    trace_half<0, 0>(r1, kp, mu, tr, sm);
    c1_sweep<0>(r1, logdet);             // r1 now holds multipliers c_0..31

    // ---- panel 2 (cols 32..63) ----
    __syncthreads();                     // all waves done reading panel-1 LDS
    float r2[HN];
    stage(32);
    __syncthreads();
    fillp<0>(r2, plane, lane);

    trace_half<32, 0>(r2, kp + 32, mu, tr, sm);
    rep_sweep<0>(r2, r1);                // deferred right-half updates
    solo_sweep<0>(r2, logdet);           // trailing 32x32 pivots

    float contrib = tr + mu * sm;
#pragma unroll
    for (int off = 32; off >= 1; off >>= 1) contrib += __shfl_xor(contrib, off, 64);

    if (lane == 0) {
        float klp = 0.5f * (logdetK[l] - logdet - (float)TN + contrib);
        atomicAdd(&out[b], klp);
    }
}

// ======================== fused k_ll + k_kinv (R11-R15, unchanged) =========
template<int J>
__device__ __forceinline__ void pan_load(float (&p)[HN], const float* __restrict__ Kmat,
                                         int i, int l, int jbase) {
    if constexpr (J < HN) {
        p[J] = Kmat[(i * TN + jbase + J) * LN + l];
        pan_load<J + 1>(p, Kmat, i, l, jbase);
    }
}
template<int K, int J>
__device__ __forceinline__ void ki_upd(float (&a)[HN], float c) {
    if constexpr (J < HN) {
        a[J] = fmaf(-c, bcastf(a[J], K), a[J]);
        ki_upd<K, J + 1>(a, c);
    }
}
template<int K>
__device__ __forceinline__ void ki_a1sweep(float (&a1)[HN], float& ld, float& piv, int i) {
    if constexpr (K < HN) {
        float dkk = bcastf(a1[K], K);
        ld += __logf(dkk);
        if (i == K) piv = dkk;
        float c = (i == K) ? 0.0f : a1[K] * __builtin_amdgcn_rcpf(dkk);
        ki_upd<K, K + 1>(a1, c);
        a1[K] = c;
        ki_a1sweep<K + 1>(a1, ld, piv, i);
    }
}
template<int K>
__device__ __forceinline__ void ki_replay(float (&a2)[HN], const float (&a1)[HN]) {
    if constexpr (K < HN) {
        ki_upd<K, 0>(a2, a1[K]);
        ki_replay<K + 1>(a2, a1);
    }
}
template<int Q, int J>
__device__ __forceinline__ void ki_upd2(float (&a2)[HN], float c) {
    if constexpr (J < HN) {
        a2[J] = fmaf(-c, bcastf(a2[J], 32 + Q), a2[J]);
        ki_upd2<Q, J + 1>(a2, c);
    }
}
template<int Q>
__device__ __forceinline__ void ki_a2sweep(float (&a2)[HN], float& ld, float& piv, int i) {
    if constexpr (Q < HN) {
        float dkk = bcastf(a2[Q], 32 + Q);
        ld += __logf(dkk);
        if (i == 32 + Q) piv = dkk;
        float c = (i == 32 + Q) ? 0.0f : a2[Q] * __builtin_amdgcn_rcpf(dkk);
        ki_upd2<Q, Q + 1>(a2, c);
        a2[Q] = c;
        ki_a2sweep<Q + 1>(a2, ld, piv, i);
    }
}
template<int J>
__device__ __forceinline__ void g1_init(float (&g)[HN], int i) {
    if constexpr (J < HN) { g[J] = (J == i) ? 1.0f : 0.0f; g1_init<J + 1>(g, i); }
}
template<int K, int J>
__device__ __forceinline__ void g1_updA(float (&g)[HN], float c) {
    if constexpr (J <= K) {
        g[J] = fmaf(-c, bcastf(g[J], K), g[J]);
        g1_updA<K, J + 1>(g, c);
    }
}
template<int K>
__device__ __forceinline__ void g1_phase1(float (&g)[HN], const float (&a1)[HN]) {
    if constexpr (K < HN) {
        g1_updA<K, 0>(g, a1[K]);
        g1_phase1<K + 1>(g, a1);
    }
}
template<int Q, int J>
__device__ __forceinline__ void g1_updB(float (&g)[HN], float c) {
    if constexpr (J < HN) {
        g[J] = fmaf(-c, bcastf(g[J], 32 + Q), g[J]);
        g1_updB<Q, J + 1>(g, c);
    }
}
template<int Q>
__device__ __forceinline__ void g1_phase2(float (&g)[HN], const float (&a2)[HN]) {
    if constexpr (Q < HN) {
        g1_updB<Q, 0>(g, a2[Q]);
        g1_phase2<Q + 1>(g, a2);
    }
}
template<int J>
__device__ __forceinline__ void g2_init(float (&g)[HN], int i) {
    if constexpr (J < HN) { g[J] = (32 + J == i) ? 1.0f : 0.0f; g2_init<J + 1>(g, i); }
}
template<int Q, int J>
__device__ __forceinline__ void g2_upd(float (&g)[HN], float c) {
    if constexpr (J <= Q) {
        g[J] = fmaf(-c, bcastf(g[J], 32 + Q), g[J]);
        g2_upd<Q, J + 1>(g, c);
    }
}
template<int Q>
__device__ __forceinline__ void g2_phase(float (&g)[HN], const float (&a2)[HN]) {
    if constexpr (Q < HN) {
        g2_upd<Q, 0>(g, a2[Q]);
        g2_phase<Q + 1>(g, a2);
    }
}
template<int J>
__device__ __forceinline__ void pan_out(const float (&g)[HN], float rdi,
                                        float* __restrict__ dst) {
    if constexpr (J < HN) {
        dst[J] = g[J] * rdi;
        pan_out<J + 1>(g, rdi, dst);
    }
}

__global__ __launch_bounds__(256)
void k_ll_kinv(const float* __restrict__ X,
               const float* __restrict__ Mn,
               const float* __restrict__ R,
               const float* __restrict__ Kmat,
               float* __restrict__ kinv,
               float* __restrict__ logdetK,
               float* __restrict__ out) {
    if (blockIdx.x < 64) {
        // 2 blocks per latent: both redo the sweeps, split the reconstruction
        if (threadIdx.x >= 64) return;
        const int l = blockIdx.x >> 1;
        const int half = blockIdx.x & 1;
        const int i = threadIdx.x;       // row

        float ld = 0.0f, piv = 1.0f;
        float a1[HN], a2[HN];
        pan_load<0>(a1, Kmat, i, l, 0);
        ki_a1sweep<0>(a1, ld, piv, i);
        pan_load<0>(a2, Kmat, i, l, 32);
        ki_replay<0>(a2, a1);
        ki_a2sweep<0>(a2, ld, piv, i);
        float rdi = __builtin_amdgcn_rcpf(piv);
        if (half == 0) {
            float g1[HN];
            g1_init<0>(g1, i);
            g1_phase1<0>(g1, a1);
            g1_phase2<0>(g1, a2);
            pan_out<0>(g1, rdi, kinv + l * (TN * TN) + i * TN);
        } else {
            float g2[HN];
            g2_init<0>(g2, i);
            g2_phase<0>(g2, a2);
            pan_out<0>(g2, rdi, kinv + l * (TN * TN) + i * TN + 32);
            if (i == 0) logdetK[l] = ld;
        }
        return;
    }

    // ---- log-likelihood block (b,s) ----
    int hw = blockIdx.x - 64;            // 1024 blocks
    int g = (hw & 7) * 128 + (hw >> 3);
    int b = g >> 2, s = g & 3;
    int tid = threadIdx.x;

    const float4* xp = (const float4*)(X + (size_t)b * TN * DN);
    const float4* mp = (const float4*)(Mn + ((size_t)(b * SN + s) * TN) * DN);

    int c = tid & 31;
    float4 rv = ((const float4*)R)[c];
    float4 ri = make_float4(1.0f / rv.x, 1.0f / rv.y, 1.0f / rv.z, 1.0f / rv.w);

    float acc = 0.0f;
#pragma unroll
    for (int it = 0; it < (TN * DN / 4) / 256; ++it) {
        int f = tid + it * 256;
        float4 xv = xp[f];
        float4 mv = mp[f];
        float dx = xv.x - mv.x; acc = fmaf(dx * dx, ri.x, acc);
        float dy = xv.y - mv.y; acc = fmaf(dy * dy, ri.y, acc);
        float dz = xv.z - mv.z; acc = fmaf(dz * dz, ri.z, acc);
        float dw = xv.w - mv.w; acc = fmaf(dw * dw, ri.w, acc);
    }
#pragma unroll
    for (int off = 32; off >= 1; off >>= 1) acc += __shfl_xor(acc, off, 64);

    __shared__ float wsum[4];
    if ((tid & 63) == 0) wsum[tid >> 6] = acc;
    __syncthreads();
    if (tid == 0) {
        float q = wsum[0] + wsum[1] + wsum[2] + wsum[3];
        float val = q * (0.5f / SN);
        if (s == 0) {
            float slr = 0.0f;
#pragma unroll
            for (int d = 0; d < DN; ++d) slr += __logf(R[d]);
            val += 0.5f * (float)TN * (slr + (float)DN * LOG2PI);
        }
        atomicAdd(&out[b], val);
    }
}

// ---------------------------------------------------------------------------
extern "C" void kernel_launch(void* const* d_in, const int* in_sizes, int n_in,
                              void* d_out, int out_size, void* d_ws, size_t ws_size,
                              hipStream_t stream) {
    const float* X   = (const float*)d_in[0];  // [B,T,D]
    const float* Mn  = (const float*)d_in[1];  // [B,S,T,D]
    const float* R   = (const float*)d_in[2];  // [D]
    const float* mus = (const float*)d_in[3];  // [B,T,L]
    const float* Sg  = (const float*)d_in[4];  // [B,T,T,L]
    const float* Km  = (const float*)d_in[5];  // [T,T,L]
    float* out = (float*)d_out;                // [B] fp32

    float* kinv = (float*)d_ws;                // 32*4096 floats = 512 KB
    float* ldK  = kinv + LN * TN * TN;         // 32 floats

    hipMemsetAsync(d_out, 0, BN * sizeof(float), stream);
    k_ll_kinv<<<64 + BN * SN, 256, 0, stream>>>(X, Mn, R, Km, kinv, ldK, out);
    k_chol<<<BN * 8, 256, 0, stream>>>(Sg, mus, kinv, ldK, out);
}

// Round 17
// 138.347 us; speedup vs baseline: 1.7871x; 1.0093x over previous
//
#include <hip/hip_runtime.h>
#include <math.h>

// Problem constants
#define BN 256
#define TN 64
#define LN 32
#define DN 128
#define SN 4
#define HN 32   // column-panel width for the blocked elimination

#define LOG2PI 1.8378770664093453f

__device__ __forceinline__ float bcastf(float v, int lane) {
    return __builtin_bit_cast(float, __builtin_amdgcn_readlane(__builtin_bit_cast(int, v), lane));
}

// ===========================================================================
// Lessons R1-R16 (final synthesis):
//  * Register-array subscripts must be compile-time constants (templates).
//  * Min-occupancy attrs -> scratch storm (R9). f32x2/asm -> VGPR bloat
//    (R10). bf16-packed mults -> VGPR 68 (R11, worse than plain floats).
//    Per-step LDS publish -> latency-serial (R13/R15). ds_bpermute == cost
//    of readlane (R16). Every cross-lane broadcast costs ~8 issue cycles;
//    the ~2.1k broadcasts/wave are this algorithm's floor.
//  * BEST MEASURED k_chol = R8: readlane sweeps, float dead-slot
//    multipliers, 32KB single-shot panel staging, no attributes -> 117us,
//    VGPR 52, zero scratch. This round: R8 k_chol verbatim + the proven
//    2-block-kinv kernel-1 (R10-R16). Pure consolidation.
// ===========================================================================

// LDS plane layout: [64 rows][8 chunks][4 dwords]; chunk q of row i at
// position (q + i + (i>>3)) & 7 -> conflict-free b128 fills & staging stores.
__device__ __forceinline__ int chunk_pos(int q, int i) { return (q + i + (i >> 3)) & 7; }

// ---- shared template helpers (R8-proven) ---------------------------------
template<int Q>
__device__ __forceinline__ void fillp(float (&r)[HN], const float* plane, int l) {
    if constexpr (Q < 8) {
        const float4 v = *(const float4*)(plane + l * 32 + chunk_pos(Q, l) * 4);
        r[4 * Q + 0] = v.x; r[4 * Q + 1] = v.y;
        r[4 * Q + 2] = v.z; r[4 * Q + 3] = v.w;
        fillp<Q + 1>(r, plane, l);
    }
}
template<int JBASE, int J4>
__device__ __forceinline__ void trace_half(const float (&r)[HN], const float* __restrict__ kp,
                                           float mu, float& tr, float& sm) {
    if constexpr (J4 < 8) {
        float4 kv = *(const float4*)(kp + 4 * J4);
        tr = fmaf(kv.x, r[4 * J4 + 0], tr); sm = fmaf(kv.x, bcastf(mu, JBASE + 4 * J4 + 0), sm);
        tr = fmaf(kv.y, r[4 * J4 + 1], tr); sm = fmaf(kv.y, bcastf(mu, JBASE + 4 * J4 + 1), sm);
        tr = fmaf(kv.z, r[4 * J4 + 2], tr); sm = fmaf(kv.z, bcastf(mu, JBASE + 4 * J4 + 2), sm);
        tr = fmaf(kv.w, r[4 * J4 + 3], tr); sm = fmaf(kv.w, bcastf(mu, JBASE + 4 * J4 + 3), sm);
        trace_half<JBASE, J4 + 1>(r, kp, mu, tr, sm);
    }
}

// ---- k_chol sweeps (R8-proven: scalar readlane, float dead-slot mults) ---
// pivots 0..31 on cols 0..31; symmetric trailing read: A[K][J] = lane J's r1[K].
template<int K, int J>
__device__ __forceinline__ void c1_upd(float (&r1)[HN], float c) {
    if constexpr (J < HN) {
        r1[J] = fmaf(-c, bcastf(r1[K], J), r1[J]);
        c1_upd<K, J + 1>(r1, c);
    }
}
template<int K>
__device__ __forceinline__ void c1_sweep(float (&r1)[HN], float& logdet) {
    if constexpr (K < HN) {
        float dkk = bcastf(r1[K], K);
        logdet += __logf(dkk);
        float c = r1[K] * __builtin_amdgcn_rcpf(dkk);
        c1_upd<K, K + 1>(r1, c);
        r1[K] = c;                          // multiplier -> dead slot
        c1_sweep<K + 1>(r1, logdet);
    }
}
// replay pivots 0..31 onto cols 32..63; pivot row K's right half = lane K's
// r2 (exact through step K; its self-update happens after the bcast read).
template<int K, int J>
__device__ __forceinline__ void rep_upd(float (&r2)[HN], float c) {
    if constexpr (J < HN) {
        r2[J] = fmaf(-c, bcastf(r2[J], K), r2[J]);
        rep_upd<K, J + 1>(r2, c);
    }
}
template<int K>
__device__ __forceinline__ void rep_sweep(float (&r2)[HN], const float (&r1)[HN]) {
    if constexpr (K < HN) {
        rep_upd<K, 0>(r2, r1[K]);           // c from own stored multiplier
        rep_sweep<K + 1>(r2, r1);
    }
}
// pivots 32..63 on trailing 32x32 (lanes 32..63 hold the Schur rows)
template<int Q, int J>
__device__ __forceinline__ void solo_upd(float (&r2)[HN], float c) {
    if constexpr (J < HN) {
        r2[J] = fmaf(-c, bcastf(r2[Q], 32 + J), r2[J]);
        solo_upd<Q, J + 1>(r2, c);
    }
}
template<int Q>
__device__ __forceinline__ void solo_sweep(float (&r2)[HN], float& logdet) {
    if constexpr (Q < HN) {
        float dkk = bcastf(r2[Q], 32 + Q);
        logdet += __logf(dkk);
        float c = r2[Q] * __builtin_amdgcn_rcpf(dkk);
        solo_upd<Q, Q + 1>(r2, c);
        solo_sweep<Q + 1>(r2, logdet);
    }
}

// ---------------------------------------------------------------------------
// k_chol: block = 256 threads = 4 waves = one (b, l-quad). R8's proven
// staging: 4 planes x 64x32 panel = 32 KB, reused panel1 -> panel2.
// ---------------------------------------------------------------------------
__global__ __launch_bounds__(256)
void k_chol(const float* __restrict__ Sg,
            const float* __restrict__ mus,
            const float* __restrict__ kinv,
            const float* __restrict__ logdetK,
            float* __restrict__ out) {
    __shared__ float st[4 * 2048];       // 32 KB

    int hw = blockIdx.x;                 // 2048 blocks
    int g = (hw & 7) * 256 + (hw >> 3);  // XCD x owns b in [x*32, x*32+32)
    int b = g >> 3, lg = g & 7;          // lg = l-quad 0..7

    int tid = threadIdx.x;
    int w = tid >> 6, lane = tid & 63;   // wave w <-> l = lg*4 + w; lane = row
    int l = lg * 4 + w;

    float mu = mus[((size_t)b * TN + lane) * LN + l];
    const float* kp = kinv + l * (TN * TN) + lane * TN;
    const float* plane = &st[w * 2048];

    // stage a 64-row x 32-col panel (cols c0..c0+31)
    auto stage = [&](int c0) {
#pragma unroll
        for (int it = 0; it < 8; ++it) {
            int m_ = tid + it * 256;     // 0..2047
            int j = m_ & 31, i = m_ >> 5;
            const float* gp = Sg + ((((size_t)b * TN + i) * TN + c0 + j) * LN + lg * 4);
            float4 v = *(const float4*)gp;
            int off = i * 32 + chunk_pos(j >> 2, i) * 4 + (j & 3);
            st[0 * 2048 + off] = v.x;
            st[1 * 2048 + off] = v.y;
            st[2 * 2048 + off] = v.z;
            st[3 * 2048 + off] = v.w;
        }
    };

    float tr = 0.0f, sm = 0.0f, logdet = 0.0f;
    float r1[HN];

    // ---- panel 1 (cols 0..31) ----
    stage(0);
    __syncthreads();
    fillp<0>(r1, plane, lane);

    trace_half<0, 0>(r1, kp, mu, tr, sm);
    c1_sweep<0>(r1, logdet);             // r1 now holds multipliers c_0..31

    // ---- panel 2 (cols 32..63) ----
    __syncthreads();                     // all waves done reading panel-1 LDS
    float r2[HN];
    stage(32);
    __syncthreads();
    fillp<0>(r2, plane, lane);

    trace_half<32, 0>(r2, kp + 32, mu, tr, sm);
    rep_sweep<0>(r2, r1);                // deferred right-half updates
    solo_sweep<0>(r2, logdet);           // trailing 32x32 pivots

    float contrib = tr + mu * sm;
#pragma unroll
    for (int off = 32; off >= 1; off >>= 1) contrib += __shfl_xor(contrib, off, 64);

    if (lane == 0) {
        float klp = 0.5f * (logdetK[l] - logdet - (float)TN + contrib);
        atomicAdd(&out[b], klp);
    }
}

// ======================== fused k_ll + k_kinv (R10-R16, unchanged) =========
template<int J>
__device__ __forceinline__ void pan_load(float (&p)[HN], const float* __restrict__ Kmat,
                                         int i, int l, int jbase) {
    if constexpr (J < HN) {
        p[J] = Kmat[(i * TN + jbase + J) * LN + l];
        pan_load<J + 1>(p, Kmat, i, l, jbase);
    }
}
template<int K, int J>
__device__ __forceinline__ void ki_upd(float (&a)[HN], float c) {
    if constexpr (J < HN) {
        a[J] = fmaf(-c, bcastf(a[J], K), a[J]);
        ki_upd<K, J + 1>(a, c);
    }
}
template<int K>
__device__ __forceinline__ void ki_a1sweep(float (&a1)[HN], float& ld, float& piv, int i) {
    if constexpr (K < HN) {
        float dkk = bcastf(a1[K], K);
        ld += __logf(dkk);
        if (i == K) piv = dkk;
        float c = (i == K) ? 0.0f : a1[K] * __builtin_amdgcn_rcpf(dkk);
        ki_upd<K, K + 1>(a1, c);
        a1[K] = c;
        ki_a1sweep<K + 1>(a1, ld, piv, i);
    }
}
template<int K>
__device__ __forceinline__ void ki_replay(float (&a2)[HN], const float (&a1)[HN]) {
    if constexpr (K < HN) {
        ki_upd<K, 0>(a2, a1[K]);
        ki_replay<K + 1>(a2, a1);
    }
}
template<int Q, int J>
__device__ __forceinline__ void ki_upd2(float (&a2)[HN], float c) {
    if constexpr (J < HN) {
        a2[J] = fmaf(-c, bcastf(a2[J], 32 + Q), a2[J]);
        ki_upd2<Q, J + 1>(a2, c);
    }
}
template<int Q>
__device__ __forceinline__ void ki_a2sweep(float (&a2)[HN], float& ld, float& piv, int i) {
    if constexpr (Q < HN) {
        float dkk = bcastf(a2[Q], 32 + Q);
        ld += __logf(dkk);
        if (i == 32 + Q) piv = dkk;
        float c = (i == 32 + Q) ? 0.0f : a2[Q] * __builtin_amdgcn_rcpf(dkk);
        ki_upd2<Q, Q + 1>(a2, c);
        a2[Q] = c;
        ki_a2sweep<Q + 1>(a2, ld, piv, i);
    }
}
template<int J>
__device__ __forceinline__ void g1_init(float (&g)[HN], int i) {
    if constexpr (J < HN) { g[J] = (J == i) ? 1.0f : 0.0f; g1_init<J + 1>(g, i); }
}
template<int K, int J>
__device__ __forceinline__ void g1_updA(float (&g)[HN], float c) {
    if constexpr (J <= K) {
        g[J] = fmaf(-c, bcastf(g[J], K), g[J]);
        g1_updA<K, J + 1>(g, c);
    }
}
template<int K>
__device__ __forceinline__ void g1_phase1(float (&g)[HN], const float (&a1)[HN]) {
    if constexpr (K < HN) {
        g1_updA<K, 0>(g, a1[K]);
        g1_phase1<K + 1>(g, a1);
    }
}
template<int Q, int J>
__device__ __forceinline__ void g1_updB(float (&g)[HN], float c) {
    if constexpr (J < HN) {
        g[J] = fmaf(-c, bcastf(g[J], 32 + Q), g[J]);
        g1_updB<Q, J + 1>(g, c);
    }
}
template<int Q>
__device__ __forceinline__ void g1_phase2(float (&g)[HN], const float (&a2)[HN]) {
    if constexpr (Q < HN) {
        g1_updB<Q, 0>(g, a2[Q]);
        g1_phase2<Q + 1>(g, a2);
    }
}
template<int J>
__device__ __forceinline__ void g2_init(float (&g)[HN], int i) {
    if constexpr (J < HN) { g[J] = (32 + J == i) ? 1.0f : 0.0f; g2_init<J + 1>(g, i); }
}
template<int Q, int J>
__device__ __forceinline__ void g2_upd(float (&g)[HN], float c) {
    if constexpr (J <= Q) {
        g[J] = fmaf(-c, bcastf(g[J], 32 + Q), g[J]);
        g2_upd<Q, J + 1>(g, c);
    }
}
template<int Q>
__device__ __forceinline__ void g2_phase(float (&g)[HN], const float (&a2)[HN]) {
    if constexpr (Q < HN) {
        g2_upd<Q, 0>(g, a2[Q]);
        g2_phase<Q + 1>(g, a2);
    }
}
template<int J>
__device__ __forceinline__ void pan_out(const float (&g)[HN], float rdi,
                                        float* __restrict__ dst) {
    if constexpr (J < HN) {
        dst[J] = g[J] * rdi;
        pan_out<J + 1>(g, rdi, dst);
    }
}

__global__ __launch_bounds__(256)
void k_ll_kinv(const float* __restrict__ X,
               const float* __restrict__ Mn,
               const float* __restrict__ R,
               const float* __restrict__ Kmat,
               float* __restrict__ kinv,
               float* __restrict__ logdetK,
               float* __restrict__ out) {
    if (blockIdx.x < 64) {
        // 2 blocks per latent: both redo the sweeps, split the reconstruction
        if (threadIdx.x >= 64) return;
        const int l = blockIdx.x >> 1;
        const int half = blockIdx.x & 1;
        const int i = threadIdx.x;       // row

        float ld = 0.0f, piv = 1.0f;
        float a1[HN], a2[HN];
        pan_load<0>(a1, Kmat, i, l, 0);
        ki_a1sweep<0>(a1, ld, piv, i);
        pan_load<0>(a2, Kmat, i, l, 32);
        ki_replay<0>(a2, a1);
        ki_a2sweep<0>(a2, ld, piv, i);
        float rdi = __builtin_amdgcn_rcpf(piv);
        if (half == 0) {
            float g1[HN];
            g1_init<0>(g1, i);
            g1_phase1<0>(g1, a1);
            g1_phase2<0>(g1, a2);
            pan_out<0>(g1, rdi, kinv + l * (TN * TN) + i * TN);
        } else {
            float g2[HN];
            g2_init<0>(g2, i);
            g2_phase<0>(g2, a2);
            pan_out<0>(g2, rdi, kinv + l * (TN * TN) + i * TN + 32);
            if (i == 0) logdetK[l] = ld;
        }
        return;
    }

    // ---- log-likelihood block (b,s) ----
    int hw = blockIdx.x - 64;            // 1024 blocks
    int g = (hw & 7) * 128 + (hw >> 3);
    int b = g >> 2, s = g & 3;
    int tid = threadIdx.x;

    const float4* xp = (const float4*)(X + (size_t)b * TN * DN);
    const float4* mp = (const float4*)(Mn + ((size_t)(b * SN + s) * TN) * DN);

    int c = tid & 31;
    float4 rv = ((const float4*)R)[c];
    float4 ri = make_float4(1.0f / rv.x, 1.0f / rv.y, 1.0f / rv.z, 1.0f / rv.w);

    float acc = 0.0f;
#pragma unroll
    for (int it = 0; it < (TN * DN / 4) / 256; ++it) {
        int f = tid + it * 256;
        float4 xv = xp[f];
        float4 mv = mp[f];
        float dx = xv.x - mv.x; acc = fmaf(dx * dx, ri.x, acc);
        float dy = xv.y - mv.y; acc = fmaf(dy * dy, ri.y, acc);
        float dz = xv.z - mv.z; acc = fmaf(dz * dz, ri.z, acc);
        float dw = xv.w - mv.w; acc = fmaf(dw * dw, ri.w, acc);
    }
#pragma unroll
    for (int off = 32; off >= 1; off >>= 1) acc += __shfl_xor(acc, off, 64);

    __shared__ float wsum[4];
    if ((tid & 63) == 0) wsum[tid >> 6] = acc;
    __syncthreads();
    if (tid == 0) {
        float q = wsum[0] + wsum[1] + wsum[2] + wsum[3];
        float val = q * (0.5f / SN);
        if (s == 0) {
            float slr = 0.0f;
#pragma unroll
            for (int d = 0; d < DN; ++d) slr += __logf(R[d]);
            val += 0.5f * (float)TN * (slr + (float)DN * LOG2PI);
        }
        atomicAdd(&out[b], val);
    }
}

// ---------------------------------------------------------------------------
extern "C" void kernel_launch(void* const* d_in, const int* in_sizes, int n_in,
                              void* d_out, int out_size, void* d_ws, size_t ws_size,
                              hipStream_t stream) {
    const float* X   = (const float*)d_in[0];  // [B,T,D]
    const float* Mn  = (const float*)d_in[1];  // [B,S,T,D]
    const float* R   = (const float*)d_in[2];  // [D]
    const float* mus = (const float*)d_in[3];  // [B,T,L]
    const float* Sg  = (const float*)d_in[4];  // [B,T,T,L]
    const float* Km  = (const float*)d_in[5];  // [T,T,L]
    float* out = (float*)d_out;                // [B] fp32

    float* kinv = (float*)d_ws;                // 32*4096 floats = 512 KB
    float* ldK  = kinv + LN * TN * TN;         // 32 floats

    hipMemsetAsync(d_out, 0, BN * sizeof(float), stream);
    k_ll_kinv<<<64 + BN * SN, 256, 0, stream>>>(X, Mn, R, Km, kinv, ldK, out);
    k_chol<<<BN * 8, 256, 0, stream>>>(Sg, mus, kinv, ldK, out);
}

// Round 18
// 134.080 us; speedup vs baseline: 1.8439x; 1.0318x over previous
//
#include <hip/hip_runtime.h>
#include <math.h>

// Problem constants
#define BN 256
#define TN 64
#define LN 32
#define DN 128
#define SN 4
#define HN 32   // column-panel width for the blocked elimination

#define LOG2PI 1.8378770664093453f

__device__ __forceinline__ float bcastf(float v, int lane) {
    return __builtin_bit_cast(float, __builtin_amdgcn_readlane(__builtin_bit_cast(int, v), lane));
}

// ===========================================================================
// Lessons R1-R17:
//  * Register-array subscripts must be compile-time constants (templates).
//  * Min-occupancy attrs -> scratch storm (R9). f32x2/asm -> VGPR bloat
//    (R10). bf16 mults -> +16 VGPR (R11). LDS publish -> latency-serial
//    (R13/R15). ds_bpermute == readlane (R16).
//  * R17 (consolidated best): k_chol 124us, VGPR 60, VALUBusy 58%.
//  * THIS round's hypothesis test: VALUBusy 58% (not ~100%) suggests the
//    ~10cyc/broadcast-pair is an UNHIDDEN SGPR-write->VALU-read hazard,
//    not pure issue cost. Batch 8 independent readlanes -> s[0..7] (SGPRs)
//    -> 8 fmas, so the hazards overlap within one wave. Pure reorder of an
//    independent read set (sources never written inside a sweep) -> zero
//    semantic change. If flat: cross-lane issue floor is proven.
// ===========================================================================

// LDS plane layout: [64 rows][8 chunks][4 dwords]; chunk q of row i at
// position (q + i + (i>>3)) & 7 -> conflict-free b128 fills & staging stores.
__device__ __forceinline__ int chunk_pos(int q, int i) { return (q + i + (i >> 3)) & 7; }

// ---- shared template helpers (R8/R17-proven) -----------------------------
template<int Q>
__device__ __forceinline__ void fillp(float (&r)[HN], const float* plane, int l) {
    if constexpr (Q < 8) {
        const float4 v = *(const float4*)(plane + l * 32 + chunk_pos(Q, l) * 4);
        r[4 * Q + 0] = v.x; r[4 * Q + 1] = v.y;
        r[4 * Q + 2] = v.z; r[4 * Q + 3] = v.w;
        fillp<Q + 1>(r, plane, l);
    }
}
template<int JBASE, int J4>
__device__ __forceinline__ void trace_half(const float (&r)[HN], const float* __restrict__ kp,
                                           float mu, float& tr, float& sm) {
    if constexpr (J4 < 8) {
        float4 kv = *(const float4*)(kp + 4 * J4);
        tr = fmaf(kv.x, r[4 * J4 + 0], tr); sm = fmaf(kv.x, bcastf(mu, JBASE + 4 * J4 + 0), sm);
        tr = fmaf(kv.y, r[4 * J4 + 1], tr); sm = fmaf(kv.y, bcastf(mu, JBASE + 4 * J4 + 1), sm);
        tr = fmaf(kv.z, r[4 * J4 + 2], tr); sm = fmaf(kv.z, bcastf(mu, JBASE + 4 * J4 + 2), sm);
        tr = fmaf(kv.w, r[4 * J4 + 3], tr); sm = fmaf(kv.w, bcastf(mu, JBASE + 4 * J4 + 3), sm);
        trace_half<JBASE, J4 + 1>(r, kp, mu, tr, sm);
    }
}

// ---- batched-broadcast machinery -----------------------------------------
// c1/solo pattern: fixed source register, varying lane.
template<int K, int J, int E>
__device__ __forceinline__ void g8_fixreg(const float (&r)[HN], float (&s)[8], int loff) {
    if constexpr (E < 8 && J + E < HN) {
        s[E] = bcastf(r[K], loff + J + E);
        g8_fixreg<K, J, E + 1>(r, s, loff);
    }
}
template<int J, int E>
__device__ __forceinline__ void a8(float (&r)[HN], const float (&s)[8], float c) {
    if constexpr (E < 8 && J + E < HN) {
        r[J + E] = fmaf(-c, s[E], r[J + E]);
        a8<J, E + 1>(r, s, c);
    }
}
// rep pattern: varying source register, fixed lane K.
template<int K, int J, int E>
__device__ __forceinline__ void g8_fixlane(const float (&r)[HN], float (&s)[8]) {
    if constexpr (E < 8 && J + E < HN) {
        s[E] = bcastf(r[J + E], K);
        g8_fixlane<K, J, E + 1>(r, s);
    }
}

// ---- k_chol sweeps (batched; math identical to R8/R17) -------------------
// pivots 0..31 on cols 0..31; symmetric trailing read: A[K][J] = lane J's r1[K].
// r1[K] is never written inside the sweep body -> gather-then-apply is a
// pure reorder.
template<int K, int J>
__device__ __forceinline__ void c1_upd(float (&r1)[HN], float c) {
    if constexpr (J < HN) {
        float s[8];
        g8_fixreg<K, J, 0>(r1, s, 0);
        a8<J, 0>(r1, s, c);
        c1_upd<K, J + 8>(r1, c);
    }
}
template<int K>
__device__ __forceinline__ void c1_sweep(float (&r1)[HN], float& logdet) {
    if constexpr (K < HN) {
        float dkk = bcastf(r1[K], K);
        logdet += __logf(dkk);
        float c = r1[K] * __builtin_amdgcn_rcpf(dkk);
        c1_upd<K, K + 1>(r1, c);
        r1[K] = c;                          // multiplier -> dead slot
        c1_sweep<K + 1>(r1, logdet);
    }
}
// replay pivots 0..31 onto cols 32..63; pivot row K's right half = lane K's
// r2. Original code read each lane-K r2[J] before writing it; batch-gather
// reads all 8 pre-update values first -> identical (updates of r2[J'] never
// feed later gathers of r2[J] within the step).
template<int K, int J>
__device__ __forceinline__ void rep_upd(float (&r2)[HN], float c) {
    if constexpr (J < HN) {
        float s[8];
        g8_fixlane<K, J, 0>(r2, s);
        a8<J, 0>(r2, s, c);
        rep_upd<K, J + 8>(r2, c);
    }
}
template<int K>
__device__ __forceinline__ void rep_sweep(float (&r2)[HN], const float (&r1)[HN]) {
    if constexpr (K < HN) {
        rep_upd<K, 0>(r2, r1[K]);           // c from own stored multiplier
        rep_sweep<K + 1>(r2, r1);
    }
}
// pivots 32..63 on trailing 32x32 (lanes 32..63 hold the Schur rows);
// fixed source register r2[Q], lane 32+J varies; r2[Q] never written in body.
template<int Q, int J>
__device__ __forceinline__ void solo_upd(float (&r2)[HN], float c) {
    if constexpr (J < HN) {
        float s[8];
        g8_fixreg<Q, J, 0>(r2, s, 32);
        a8<J, 0>(r2, s, c);
        solo_upd<Q, J + 8>(r2, c);
    }
}
template<int Q>
__device__ __forceinline__ void solo_sweep(float (&r2)[HN], float& logdet) {
    if constexpr (Q < HN) {
        float dkk = bcastf(r2[Q], 32 + Q);
        logdet += __logf(dkk);
        float c = r2[Q] * __builtin_amdgcn_rcpf(dkk);
        solo_upd<Q, Q + 1>(r2, c);
        solo_sweep<Q + 1>(r2, logdet);
    }
}

// ---------------------------------------------------------------------------
// k_chol: block = 256 threads = 4 waves = one (b, l-quad). R8's proven
// staging: 4 planes x 64x32 panel = 32 KB, reused panel1 -> panel2.
// ---------------------------------------------------------------------------
__global__ __launch_bounds__(256)
void k_chol(const float* __restrict__ Sg,
            const float* __restrict__ mus,
            const float* __restrict__ kinv,
            const float* __restrict__ logdetK,
            float* __restrict__ out) {
    __shared__ float st[4 * 2048];       // 32 KB

    int hw = blockIdx.x;                 // 2048 blocks
    int g = (hw & 7) * 256 + (hw >> 3);  // XCD x owns b in [x*32, x*32+32)
    int b = g >> 3, lg = g & 7;          // lg = l-quad 0..7

    int tid = threadIdx.x;
    int w = tid >> 6, lane = tid & 63;   // wave w <-> l = lg*4 + w; lane = row
    int l = lg * 4 + w;

    float mu = mus[((size_t)b * TN + lane) * LN + l];
    const float* kp = kinv + l * (TN * TN) + lane * TN;
    const float* plane = &st[w * 2048];

    // stage a 64-row x 32-col panel (cols c0..c0+31)
    auto stage = [&](int c0) {
#pragma unroll
        for (int it = 0; it < 8; ++it) {
            int m_ = tid + it * 256;     // 0..2047
            int j = m_ & 31, i = m_ >> 5;
            const float* gp = Sg + ((((size_t)b * TN + i) * TN + c0 + j) * LN + lg * 4);
            float4 v = *(const float4*)gp;
            int off = i * 32 + chunk_pos(j >> 2, i) * 4 + (j & 3);
            st[0 * 2048 + off] = v.x;
            st[1 * 2048 + off] = v.y;
            st[2 * 2048 + off] = v.z;
            st[3 * 2048 + off] = v.w;
        }
    };

    float tr = 0.0f, sm = 0.0f, logdet = 0.0f;
    float r1[HN];

    // ---- panel 1 (cols 0..31) ----
    stage(0);
    __syncthreads();
    fillp<0>(r1, plane, lane);

    trace_half<0, 0>(r1, kp, mu, tr, sm);
    c1_sweep<0>(r1, logdet);             // r1 now holds multipliers c_0..31

    // ---- panel 2 (cols 32..63) ----
    __syncthreads();                     // all waves done reading panel-1 LDS
    float r2[HN];
    stage(32);
    __syncthreads();
    fillp<0>(r2, plane, lane);

    trace_half<32, 0>(r2, kp + 32, mu, tr, sm);
    rep_sweep<0>(r2, r1);                // deferred right-half updates
    solo_sweep<0>(r2, logdet);           // trailing 32x32 pivots

    float contrib = tr + mu * sm;
#pragma unroll
    for (int off = 32; off >= 1; off >>= 1) contrib += __shfl_xor(contrib, off, 64);

    if (lane == 0) {
        float klp = 0.5f * (logdetK[l] - logdet - (float)TN + contrib);
        atomicAdd(&out[b], klp);
    }
}

// ======================== fused k_ll + k_kinv (R10-R17, unchanged) =========
template<int J>
__device__ __forceinline__ void pan_load(float (&p)[HN], const float* __restrict__ Kmat,
                                         int i, int l, int jbase) {
    if constexpr (J < HN) {
        p[J] = Kmat[(i * TN + jbase + J) * LN + l];
        pan_load<J + 1>(p, Kmat, i, l, jbase);
    }
}
template<int K, int J>
__device__ __forceinline__ void ki_upd(float (&a)[HN], float c) {
    if constexpr (J < HN) {
        a[J] = fmaf(-c, bcastf(a[J], K), a[J]);
        ki_upd<K, J + 1>(a, c);
    }
}
template<int K>
__device__ __forceinline__ void ki_a1sweep(float (&a1)[HN], float& ld, float& piv, int i) {
    if constexpr (K < HN) {
        float dkk = bcastf(a1[K], K);
        ld += __logf(dkk);
        if (i == K) piv = dkk;
        float c = (i == K) ? 0.0f : a1[K] * __builtin_amdgcn_rcpf(dkk);
        ki_upd<K, K + 1>(a1, c);
        a1[K] = c;
        ki_a1sweep<K + 1>(a1, ld, piv, i);
    }
}
template<int K>
__device__ __forceinline__ void ki_replay(float (&a2)[HN], const float (&a1)[HN]) {
    if constexpr (K < HN) {
        ki_upd<K, 0>(a2, a1[K]);
        ki_replay<K + 1>(a2, a1);
    }
}
template<int Q, int J>
__device__ __forceinline__ void ki_upd2(float (&a2)[HN], float c) {
    if constexpr (J < HN) {
        a2[J] = fmaf(-c, bcastf(a2[J], 32 + Q), a2[J]);
        ki_upd2<Q, J + 1>(a2, c);
    }
}
template<int Q>
__device__ __forceinline__ void ki_a2sweep(float (&a2)[HN], float& ld, float& piv, int i) {
    if constexpr (Q < HN) {
        float dkk = bcastf(a2[Q], 32 + Q);
        ld += __logf(dkk);
        if (i == 32 + Q) piv = dkk;
        float c = (i == 32 + Q) ? 0.0f : a2[Q] * __builtin_amdgcn_rcpf(dkk);
        ki_upd2<Q, Q + 1>(a2, c);
        a2[Q] = c;
        ki_a2sweep<Q + 1>(a2, ld, piv, i);
    }
}
template<int J>
__device__ __forceinline__ void g1_init(float (&g)[HN], int i) {
    if constexpr (J < HN) { g[J] = (J == i) ? 1.0f : 0.0f; g1_init<J + 1>(g, i); }
}
template<int K, int J>
__device__ __forceinline__ void g1_updA(float (&g)[HN], float c) {
    if constexpr (J <= K) {
        g[J] = fmaf(-c, bcastf(g[J], K), g[J]);
        g1_updA<K, J + 1>(g, c);
    }
}
template<int K>
__device__ __forceinline__ void g1_phase1(float (&g)[HN], const float (&a1)[HN]) {
    if constexpr (K < HN) {
        g1_updA<K, 0>(g, a1[K]);
        g1_phase1<K + 1>(g, a1);
    }
}
template<int Q, int J>
__device__ __forceinline__ void g1_updB(float (&g)[HN], float c) {
    if constexpr (J < HN) {
        g[J] = fmaf(-c, bcastf(g[J], 32 + Q), g[J]);
        g1_updB<Q, J + 1>(g, c);
    }
}
template<int Q>
__device__ __forceinline__ void g1_phase2(float (&g)[HN], const float (&a2)[HN]) {
    if constexpr (Q < HN) {
        g1_updB<Q, 0>(g, a2[Q]);
        g1_phase2<Q + 1>(g, a2);
    }
}
template<int J>
__device__ __forceinline__ void g2_init(float (&g)[HN], int i) {
    if constexpr (J < HN) { g[J] = (32 + J == i) ? 1.0f : 0.0f; g2_init<J + 1>(g, i); }
}
template<int Q, int J>
__device__ __forceinline__ void g2_upd(float (&g)[HN], float c) {
    if constexpr (J <= Q) {
        g[J] = fmaf(-c, bcastf(g[J], 32 + Q), g[J]);
        g2_upd<Q, J + 1>(g, c);
    }
}
template<int Q>
__device__ __forceinline__ void g2_phase(float (&g)[HN], const float (&a2)[HN]) {
    if constexpr (Q < HN) {
        g2_upd<Q, 0>(g, a2[Q]);
        g2_phase<Q + 1>(g, a2);
    }
}
template<int J>
__device__ __forceinline__ void pan_out(const float (&g)[HN], float rdi,
                                        float* __restrict__ dst) {
    if constexpr (J < HN) {
        dst[J] = g[J] * rdi;
        pan_out<J + 1>(g, rdi, dst);
    }
}

__global__ __launch_bounds__(256)
void k_ll_kinv(const float* __restrict__ X,
               const float* __restrict__ Mn,
               const float* __restrict__ R,
               const float* __restrict__ Kmat,
               float* __restrict__ kinv,
               float* __restrict__ logdetK,
               float* __restrict__ out) {
    if (blockIdx.x < 64) {
        // 2 blocks per latent: both redo the sweeps, split the reconstruction
        if (threadIdx.x >= 64) return;
        const int l = blockIdx.x >> 1;
        const int half = blockIdx.x & 1;
        const int i = threadIdx.x;       // row

        float ld = 0.0f, piv = 1.0f;
        float a1[HN], a2[HN];
        pan_load<0>(a1, Kmat, i, l, 0);
        ki_a1sweep<0>(a1, ld, piv, i);
        pan_load<0>(a2, Kmat, i, l, 32);
        ki_replay<0>(a2, a1);
        ki_a2sweep<0>(a2, ld, piv, i);
        float rdi = __builtin_amdgcn_rcpf(piv);
        if (half == 0) {
            float g1[HN];
            g1_init<0>(g1, i);
            g1_phase1<0>(g1, a1);
            g1_phase2<0>(g1, a2);
            pan_out<0>(g1, rdi, kinv + l * (TN * TN) + i * TN);
        } else {
            float g2[HN];
            g2_init<0>(g2, i);
            g2_phase<0>(g2, a2);
            pan_out<0>(g2, rdi, kinv + l * (TN * TN) + i * TN + 32);
            if (i == 0) logdetK[l] = ld;
        }
        return;
    }

    // ---- log-likelihood block (b,s) ----
    int hw = blockIdx.x - 64;            // 1024 blocks
    int g = (hw & 7) * 128 + (hw >> 3);
    int b = g >> 2, s = g & 3;
    int tid = threadIdx.x;

    const float4* xp = (const float4*)(X + (size_t)b * TN * DN);
    const float4* mp = (const float4*)(Mn + ((size_t)(b * SN + s) * TN) * DN);

    int c = tid & 31;
    float4 rv = ((const float4*)R)[c];
    float4 ri = make_float4(1.0f / rv.x, 1.0f / rv.y, 1.0f / rv.z, 1.0f / rv.w);

    float acc = 0.0f;
#pragma unroll
    for (int it = 0; it < (TN * DN / 4) / 256; ++it) {
        int f = tid + it * 256;
        float4 xv = xp[f];
        float4 mv = mp[f];
        float dx = xv.x - mv.x; acc = fmaf(dx * dx, ri.x, acc);
        float dy = xv.y - mv.y; acc = fmaf(dy * dy, ri.y, acc);
        float dz = xv.z - mv.z; acc = fmaf(dz * dz, ri.z, acc);
        float dw = xv.w - mv.w; acc = fmaf(dw * dw, ri.w, acc);
    }
#pragma unroll
    for (int off = 32; off >= 1; off >>= 1) acc += __shfl_xor(acc, off, 64);

    __shared__ float wsum[4];
    if ((tid & 63) == 0) wsum[tid >> 6] = acc;
    __syncthreads();
    if (tid == 0) {
        float q = wsum[0] + wsum[1] + wsum[2] + wsum[3];
        float val = q * (0.5f / SN);
        if (s == 0) {
            float slr = 0.0f;
#pragma unroll
            for (int d = 0; d < DN; ++d) slr += __logf(R[d]);
            val += 0.5f * (float)TN * (slr + (float)DN * LOG2PI);
        }
        atomicAdd(&out[b], val);
    }
}

// ---------------------------------------------------------------------------
extern "C" void kernel_launch(void* const* d_in, const int* in_sizes, int n_in,
                              void* d_out, int out_size, void* d_ws, size_t ws_size,
                              hipStream_t stream) {
    const float* X   = (const float*)d_in[0];  // [B,T,D]
    const float* Mn  = (const float*)d_in[1];  // [B,S,T,D]
    const float* R   = (const float*)d_in[2];  // [D]
    const float* mus = (const float*)d_in[3];  // [B,T,L]
    const float* Sg  = (const float*)d_in[4];  // [B,T,T,L]
    const float* Km  = (const float*)d_in[5];  // [T,T,L]
    float* out = (float*)d_out;                // [B] fp32

    float* kinv = (float*)d_ws;                // 32*4096 floats = 512 KB
    float* ldK  = kinv + LN * TN * TN;         // 32 floats

    hipMemsetAsync(d_out, 0, BN * sizeof(float), stream);
    k_ll_kinv<<<64 + BN * SN, 256, 0, stream>>>(X, Mn, R, Km, kinv, ldK, out);
    k_chol<<<BN * 8, 256, 0, stream>>>(Sg, mus, kinv, ldK, out);
}